// Round 8
// baseline (356.384 us; speedup 1.0000x reference)
//
#include <hip/hip_runtime.h>
#include <hip/hip_bf16.h>

// Net_22625887715641: fused conv-feats + channel-normalize + 32x32 normalized
// cross-correlation (23x23 shifts, 362x362 templates).
//
// R8 vs R7 (corr 225us @ MfmaUtil 31.6% / Occ 26%; feat ~120us):
//  - corr: BALANCED chunks: y-range = [c*367/24,(c+1)*367/24), all 24 real ->
//    grid 768 uniform = exactly 3 blocks/CU (R7: 32 no-op blocks + short tail
//    left avg ~2.3 blocks/CU resident -> Occ 26% vs 37.5% cap).
//  - feat: t-loop unrolled (kills runtime if(t==2) branch); filtb pack moved
//    to pack_kernel (coalesced 16B writes, x1 re-read via L2 ~5us) -- feat
//    epilogue had 32 scattered 2B stores/thread.
//  - absmax 9.77e-4 is x1-dominated (stable across R6 bug/fix) -> x2 has
//    large headroom for R9 fp8-MX if corr stays dominant.

typedef unsigned short ushort_t;
typedef unsigned int uint_t;
typedef __attribute__((ext_vector_type(8))) short bf16x8;    // 8 bf16 = 4 VGPRs
typedef __attribute__((ext_vector_type(4))) float f32x4;
typedef __attribute__((ext_vector_type(4))) uint_t uint4_t;
typedef __attribute__((ext_vector_type(4))) ushort_t ushortx4;

#define EPSF 2.2204460492503131e-16f
#define X1_N (32*384*384)
#define X2_N (32*32*23*23)

// filtb: [372 rows][48 xb][32 o][8 xi] bf16; row = yf+5 (yf=0..361 at rows 5..366)
#define FILTB_ELEMS (372*48*32*8)
// prevb: [32 c][385 rows][408 x] bf16; data rows 0..383 cols 0..383; zeros else
#define PREVB_ROWS 385
#define PREVB_ELEMS (32*PREVB_ROWS*408)
#define ZERO_BYTES ((size_t)(FILTB_ELEMS + PREVB_ELEMS)*2)
// fT2: fp32 [16 chp][45 rows][12] after prevb; rows 0..32 = temp (t*11+a),
// rows 33..43 = notemp (a); col 11 zero-padded.
#define FT2_ELEMS (16*45*12)

#define YMAX 367            // y-steps 0..366
#define NCHUNKS 24          // balanced: chunk c covers [c*367/24,(c+1)*367/24)
#define INV_AREA (1.0f/131044.0f)

// sB (u32 words): [dyb 4][copy 8]; copy s base = 208*s + 4*(s>>1); row stride 1668
#define SB_RS 1668
#define SB_WORDS (4*SB_RS)   // 6672 words = 26688 B -> 3 blocks/CU

// ---------------------------------------------------------------------------
// Prep: pack filters to [chp][45][12] (rows 16B-aligned, b-contiguous).
// ---------------------------------------------------------------------------
__global__ void prep_kernel(const float* __restrict__ ft, const float* __restrict__ fn,
                            float* __restrict__ fT2)
{
  const int e = blockIdx.x * 256 + threadIdx.x;
  if (e < FT2_ELEMS) {
    const int chp = e / 540;
    const int rem = e - chp * 540;
    const int row = rem / 12;
    const int j = rem - row * 12;
    float v = 0.f;
    if (j < 11) {
      if (row < 33)      v = ft[chp * 363 + row * 11 + j];        // row = t*11+a
      else if (row < 44) v = fn[chp * 121 + (row - 33) * 11 + j]; // row-33 = a
    }
    fT2[e] = v;
  }
}

// ---------------------------------------------------------------------------
// Stage 1: thread = (ch-pair chp: channels chp & chp+16) x (16-px row).
// Block 128 thr = 8 rows x 16 chpairs; px window [3][18][28] in LDS.
// mode 0: x -> x1 (fp32). mode 1: xprev -> prevb (bf16 packed).
// (filtb pack moved to pack_kernel.)
// ---------------------------------------------------------------------------
__global__ __launch_bounds__(128, 4) void feat_kernel(
    const float* __restrict__ xcur, const float* __restrict__ xprev,
    const float* __restrict__ fT2,
    float* __restrict__ out_x1, ushort_t* __restrict__ prevb)
{
  __shared__ float sPx[3 * 18 * 28];
  const int tid = threadIdx.x;
  const int chp = tid & 15;
  const int r = tid >> 4;              // 0..7
  const int j0 = blockIdx.x * 16;
  const int i0 = blockIdx.y * 8;
  const int i = i0 + r;
  const int mode = blockIdx.z;
  const float* __restrict__ xin = mode ? xprev : xcur;

  for (int e = tid; e < 3 * 18 * 26; e += 128) {
    const int t = e / 468;
    const int rem = e - t * 468;
    const int ri = rem / 26;
    const int ci = rem - ri * 26;
    sPx[(t * 18 + ri) * 28 + ci] = xin[((size_t)t * 394 + i0 + ri) * 394 + j0 + ci];
  }
  __syncthreads();

  const float* __restrict__ fbase = fT2 + chp * 540;

  float accT[16], accN[16];
#pragma unroll
  for (int p = 0; p < 16; ++p) { accT[p] = 0.f; accN[p] = 0.f; }

#pragma unroll
  for (int t = 0; t < 3; ++t) {
    for (int a = 0; a < 11; ++a) {
      const float* row = &sPx[(t * 18 + r + a) * 28];
      float wv[26];
#pragma unroll
      for (int k = 0; k < 6; ++k) {
        const f32x4 q = *(const f32x4*)(row + 4 * k);
        wv[4 * k + 0] = q[0]; wv[4 * k + 1] = q[1];
        wv[4 * k + 2] = q[2]; wv[4 * k + 3] = q[3];
      }
      wv[24] = row[24]; wv[25] = row[25];

      // hoisted vector filter loads: 3 (or 6) f32x4 per 176 (352) FMAs
      const float* fr = fbase + (t * 11 + a) * 12;
      const f32x4 fq0 = *(const f32x4*)(fr);
      const f32x4 fq1 = *(const f32x4*)(fr + 4);
      const f32x4 fq2 = *(const f32x4*)(fr + 8);
      float fv[12];
#pragma unroll
      for (int k = 0; k < 4; ++k) { fv[k] = fq0[k]; fv[4+k] = fq1[k]; fv[8+k] = fq2[k]; }
      float fv2[12];
      if (t == 2) {                       // static after t-unroll
        const float* fr2 = fbase + (33 + a) * 12;
        const f32x4 g0 = *(const f32x4*)(fr2);
        const f32x4 g1 = *(const f32x4*)(fr2 + 4);
        const f32x4 g2 = *(const f32x4*)(fr2 + 8);
#pragma unroll
        for (int k = 0; k < 4; ++k) { fv2[k] = g0[k]; fv2[4+k] = g1[k]; fv2[8+k] = g2[k]; }
      }

#pragma unroll
      for (int b = 0; b < 11; ++b) {
        const float fT = fv[b];
#pragma unroll
        for (int p = 0; p < 16; ++p) accT[p] = fmaf(wv[b + p], fT, accT[p]);
        if (t == 2) {
          const float fN = fv2[b];
#pragma unroll
          for (int p = 0; p < 16; ++p) accN[p] = fmaf(wv[b + p], fN, accN[p]);
        }
      }
    }
  }

  float o0[16], o1[16];
#pragma unroll
  for (int p = 0; p < 16; ++p) {
    const float vT = fmaxf(accT[p], 0.f) * 0.5f;   // temp: relu(conv)/2
    const float vN = fmaxf(accN[p], 0.f);
    float s = vT + vN;
    s += __shfl_xor(s, 1);  s += __shfl_xor(s, 2);
    s += __shfl_xor(s, 4);  s += __shfl_xor(s, 8); // sum over 16 chpairs = 32 ch
    const float inv = 1.f / (s + EPSF);
    o0[p] = vT * inv;
    o1[p] = vN * inv;
  }

  if (mode == 0) {
#pragma unroll
    for (int q = 0; q < 4; ++q) {
      f32x4 v0 = {o0[4*q], o0[4*q+1], o0[4*q+2], o0[4*q+3]};
      f32x4 v1 = {o1[4*q], o1[4*q+1], o1[4*q+2], o1[4*q+3]};
      *(f32x4*)(out_x1 + (size_t)chp * 147456 + i * 384 + j0 + 4 * q) = v0;
      *(f32x4*)(out_x1 + (size_t)(chp + 16) * 147456 + i * 384 + j0 + 4 * q) = v1;
    }
  } else {
#pragma unroll
    for (int q = 0; q < 4; ++q) {
      ushortx4 u0, u1;
#pragma unroll
      for (int k = 0; k < 4; ++k) {
        u0[k] = __builtin_bit_cast(ushort_t, __float2bfloat16(o0[4*q+k]));
        u1[k] = __builtin_bit_cast(ushort_t, __float2bfloat16(o1[4*q+k]));
      }
      *(ushortx4*)(prevb + ((size_t)chp * PREVB_ROWS + i) * 408 + j0 + 4*q) = u0;
      *(ushortx4*)(prevb + ((size_t)(chp + 16) * PREVB_ROWS + i) * 408 + j0 + 4*q) = u1;
    }
  }
}

// ---------------------------------------------------------------------------
// Pack x1 (fp32, cropped region) into filtb bf16 MFMA-A layout; coalesced
// 16B writes (lanes span o). Reads hit L2 (x1 just written, 18MB).
// thread e -> (rowr 5..366, xb 0..45, o 0..31); writes filtb[rowr][xb][o][0..7].
// ---------------------------------------------------------------------------
__global__ __launch_bounds__(256) void pack_kernel(
    const float* __restrict__ x1, ushort_t* __restrict__ filtb)
{
  const int e = blockIdx.x * 256 + threadIdx.x;
  if (e >= 362 * 46 * 32) return;
  const int o = e & 31;
  const int q = e >> 5;
  const int xb = q % 46;
  const int rowr = q / 46 + 5;          // 5..366
  const int i = rowr + 6;               // 11..372
  const int j0 = 11 + xb * 8;
  const float* src = x1 + (size_t)o * 147456 + i * 384 + j0;
  ushortx4 u0, u1;
#pragma unroll
  for (int k = 0; k < 4; ++k) {
    u0[k] = __builtin_bit_cast(ushort_t, __float2bfloat16((j0 + k     <= 372) ? src[k]     : 0.f));
    u1[k] = __builtin_bit_cast(ushort_t, __float2bfloat16((j0 + 4 + k <= 372) ? src[4 + k] : 0.f));
  }
  ushort_t* dst = filtb + (((size_t)(rowr * 48 + xb) * 32 + o) << 3);
  *(ushortx4*)dst = u0;
  *(ushortx4*)(dst + 4) = u1;
}

// ---------------------------------------------------------------------------
// Stage 2: correlation via 16x16x32 bf16 MFMA.
//   out[o,c,dy,dx] = sum_{y,x} filt[o][y-dy_a][x] * prev[c][y+6*dy_b][x+dx]
//   M=(dy_a,o)=192, N per block = 96: n = dyb*24+dx (dx 0..22, 23=pad)
//   K = (y outer, x 0..383).
// Block: 256 thr = 4 waves, ONE channel; wave w: Mt 3w..3w+2, all 6 Nt.
// ---------------------------------------------------------------------------
__global__ __launch_bounds__(256, 3) void corr_kernel(
    const ushort_t* __restrict__ filtb, const ushort_t* __restrict__ prevb,
    float* __restrict__ x2)
{
  __shared__ uint_t sB[SB_WORDS];        // 26688 B

  const int tid = threadIdx.x;
  const int lane = tid & 63;
  const int w = tid >> 6;                // 0..3: Mt = 3w + m3
  const int h = lane >> 4;               // quad 0..3
  const int nl = lane & 15;

  const int ch = blockIdx.x / NCHUNKS;         // 0..31
  const int chunk = blockIdx.x % NCHUNKS;      // 0..23; %8 == XCD
  const int y0 = (chunk * YMAX) / NCHUNKS;     // balanced 15-16 y-steps
  const int y1 = ((chunk + 1) * YMAX) / NCHUNKS;

  // Per-lane B-fragment word offsets (16*Kt added at use). All 16B-aligned.
  int boffW[6];
#pragma unroll
  for (int ntl = 0; ntl < 6; ++ntl) {
    const int n = ntl * 16 + nl;         // 0..95
    const int dyb = n / 24;
    const int dxr = n - 24 * dyb;
    const int dx = (dxr < 23) ? dxr : 22;      // pad lane reads valid data
    const int s = dx & 7;
    boffW[ntl] = dyb * SB_RS + s * 208 + 4 * (s >> 1) + 4 * (dx >> 3) + 4 * h;
  }

  // Staging role: 200 tasks: dyb row r4 = tid/50, word block sc = tid%50.
  const int r4 = (tid < 200) ? (tid / 50) : 0;
  const int sc = tid - 50 * ((tid < 200) ? (tid / 50) : 4);
  const bool st_act = (tid < 200);
  const uint_t* srcrow = (const uint_t*)(prevb +
      ((size_t)(ch * PREVB_ROWS + 6 * r4)) * 408);     // + y*204
  uint_t* dstb = sB + r4 * SB_RS + 4 * sc;

  f32x4 acc[3][6];
  const f32x4 zero = {0.f, 0.f, 0.f, 0.f};
#pragma unroll
  for (int a = 0; a < 3; ++a)
#pragma unroll
    for (int b = 0; b < 6; ++b) acc[a][b] = zero;

  for (int y = y0; y < y1; ++y) {
    __syncthreads();                     // prior compute done reading sB
    if (st_act) {
      const uint4_t* p4 = (const uint4_t*)(srcrow + (size_t)y * 204 + 4 * sc);
      const uint4_t lo = p4[0], hi = p4[1];
      uint_t st[8] = {lo.x, lo.y, lo.z, lo.w, hi.x, hi.y, hi.z, hi.w};
#pragma unroll
      for (int s = 0; s < 8; ++s) {
        const int p = s >> 1;
        uint4_t v;
        if ((s & 1) == 0) {
          v = uint4_t{st[p], st[p + 1], st[p + 2], st[p + 3]};
        } else {
          v = uint4_t{(st[p] >> 16)     | (st[p + 1] << 16),
                      (st[p + 1] >> 16) | (st[p + 2] << 16),
                      (st[p + 2] >> 16) | (st[p + 3] << 16),
                      (st[p + 3] >> 16) | (st[p + 4] << 16)};
        }
        *(uint4_t*)(dstb + s * 208 + 4 * (s >> 1)) = v;
      }
    }
    __syncthreads();                     // staging visible

    // Pipeline: B half-Kt double-buffered; A prefetched one full Kt ahead.
    // Both halves of iteration Kt use Af (A of Kt); rotation after half1.
    bf16x8 Af[3], Afn[3], Bf[3], Bfn[3];
#pragma unroll
    for (int m3 = 0; m3 < 3; ++m3) {
      const int Mt = 3 * w + m3;
      const int row = y - (Mt >> 1) + 5;               // in [0,371]
      const int o = ((Mt & 1) << 4) + nl;
      Af[m3] = *(const bf16x8*)(filtb + (((size_t)(row * 48 + h) * 32 + o) << 3));
    }
#pragma unroll
    for (int ntl = 0; ntl < 3; ++ntl)
      Bf[ntl] = *(const bf16x8*)(sB + boffW[ntl]);

#pragma unroll
    for (int Kt = 0; Kt < 12; ++Kt) {
      // prefetch B half1 (this Kt) and A (next Kt)
#pragma unroll
      for (int ntl = 0; ntl < 3; ++ntl)
        Bfn[ntl] = *(const bf16x8*)(sB + boffW[3 + ntl] + (Kt << 4));
      const int Ktn = (Kt < 11) ? Kt + 1 : 11;         // last prefetch unused
#pragma unroll
      for (int m3 = 0; m3 < 3; ++m3) {
        const int Mt = 3 * w + m3;
        const int row = y - (Mt >> 1) + 5;
        const int o = ((Mt & 1) << 4) + nl;
        Afn[m3] = *(const bf16x8*)(filtb + (((size_t)(row * 48 + Ktn * 4 + h) * 32 + o) << 3));
      }
      // half0 MFMAs: A(Kt) x B(Kt, ntl 0..2)
#pragma unroll
      for (int ntl = 0; ntl < 3; ++ntl)
#pragma unroll
        for (int m3 = 0; m3 < 3; ++m3)
          acc[m3][ntl] = __builtin_amdgcn_mfma_f32_16x16x32_bf16(Af[m3], Bf[ntl], acc[m3][ntl], 0, 0, 0);
      // prefetch B half0 (next Kt)
      const int Kt2 = (Kt < 11) ? Kt + 1 : 11;
#pragma unroll
      for (int ntl = 0; ntl < 3; ++ntl)
        Bf[ntl] = *(const bf16x8*)(sB + boffW[ntl] + (Kt2 << 4));
      // half1 MFMAs: A(Kt) x B(Kt, ntl 3..5)
#pragma unroll
      for (int ntl = 0; ntl < 3; ++ntl)
#pragma unroll
        for (int m3 = 0; m3 < 3; ++m3)
          acc[m3][3 + ntl] = __builtin_amdgcn_mfma_f32_16x16x32_bf16(Af[m3], Bfn[ntl], acc[m3][3 + ntl], 0, 0, 0);
      // rotate A for next Kt
#pragma unroll
      for (int m3 = 0; m3 < 3; ++m3) Af[m3] = Afn[m3];
    }
  }

  // Epilogue: scale partials, atomically accumulate into x2[o][c][dy][dx].
#pragma unroll
  for (int ntl = 0; ntl < 6; ++ntl) {
    const int n = ntl * 16 + nl;
    const int dyb = n / 24;
    const int dxr = n - 24 * dyb;
    if (dxr < 23) {
#pragma unroll
      for (int m3 = 0; m3 < 3; ++m3) {
        const int Mt = 3 * w + m3;
#pragma unroll
        for (int r = 0; r < 4; ++r) {
          const int m = Mt * 16 + h * 4 + r; // C/D: row=(lane>>4)*4+reg, col=lane&15
          const int o = m & 31;
          const int dy = (m >> 5) + 6 * dyb;
          if (dy <= 22)
            atomicAdd(&x2[((o * 32 + ch) * 23 + dy) * 23 + dxr],
                      acc[m3][ntl][r] * INV_AREA);
        }
      }
    }
  }
}

// ---------------------------------------------------------------------------
extern "C" void kernel_launch(void* const* d_in, const int* in_sizes, int n_in,
                              void* d_out, int out_size, void* d_ws, size_t ws_size,
                              hipStream_t stream)
{
  const float* x     = (const float*)d_in[0];   // [3][394][394]
  const float* xprev = (const float*)d_in[1];
  const float* ft    = (const float*)d_in[2];   // [16][3][11][11]
  const float* fn    = (const float*)d_in[3];   // [16][1][11][11]
  float* out = (float*)d_out;

  ushort_t* filtb = (ushort_t*)d_ws;
  ushort_t* prevb = filtb + FILTB_ELEMS;
  float* fT2 = (float*)(prevb + PREVB_ELEMS);   // 8640 floats

  // Zero packed buffers (establishes zero padding) and the x2 accumulator.
  hipMemsetAsync(d_ws, 0, ZERO_BYTES, stream);
  hipMemsetAsync(out + X1_N, 0, (size_t)X2_N * sizeof(float), stream);

  prep_kernel<<<dim3((FT2_ELEMS + 255) / 256), 256, 0, stream>>>(ft, fn, fT2);
  feat_kernel<<<dim3(24, 48, 2), 128, 0, stream>>>(x, xprev, fT2, out, prevb);
  pack_kernel<<<dim3((362 * 46 * 32 + 255) / 256), 256, 0, stream>>>(out, filtb);
  corr_kernel<<<dim3(32 * NCHUNKS), 256, 0, stream>>>(filtb, prevb, out + X1_N);
}